// Round 3
// baseline (190343.042 us; speedup 1.0000x reference)
//
#include <hip/hip_runtime.h>
#include <math.h>

#define DINLINE __device__ __forceinline__

DINLINE float sigmoidf_(float x) { return 1.f / (1.f + expf(-x)); }

// All scratch in static device memory — independent of ws_size.
__device__ __align__(256) float g_ws[36200000];

// ---------------- naive conv1: y1[(b*256+l)*512+o], relu(conv+bias) ----------------
__global__ void conv1_naive(const float* __restrict__ feat, const float* __restrict__ w,
                            const float* __restrict__ bias, float* __restrict__ y1) {
  int idx = blockIdx.x * 256 + threadIdx.x;           // 32*256*512 = 4,194,304
  if (idx >= 32 * 256 * 512) return;
  int o = idx & 511, l = (idx >> 9) & 255, b = idx >> 17;
  float s = bias[o];
  for (int c = 0; c < 256; ++c) {
    const float* wrow = w + ((size_t)o * 256 + c) * 5;
    for (int k = 0; k < 5; ++k) {
      int pos = 2 * l + k - 2;
      if (pos >= 0 && pos < 512) s += feat[((size_t)b * 512 + pos) * 256 + c] * wrow[k];
    }
  }
  y1[idx] = fmaxf(s, 0.f);
}

// ---------------- naive conv2: x2[(b*128+t)*512+o] ----------------
__global__ void conv2_naive(const float* __restrict__ y1, const float* __restrict__ w,
                            const float* __restrict__ bias, float* __restrict__ x2) {
  int idx = blockIdx.x * 256 + threadIdx.x;           // 32*128*512 = 2,097,152
  if (idx >= 32 * 128 * 512) return;
  int o = idx & 511, t = (idx >> 9) & 127, b = idx >> 16;
  float s = bias[o];
  for (int c = 0; c < 512; ++c) {
    const float* wrow = w + ((size_t)o * 512 + c) * 5;
    for (int k = 0; k < 5; ++k) {
      int pos = 2 * t + k - 2;
      if (pos >= 0 && pos < 256) s += y1[((size_t)b * 256 + pos) * 512 + c] * wrow[k];
    }
  }
  x2[idx] = fmaxf(s, 0.f);
}

// ---------------- naive GEMM: C[m*N+n] = sum_k A[m*K+k]*B[n*K+k] + bias ----------------
__global__ void gemm_naive(const float* __restrict__ A, const float* __restrict__ B,
                           const float* __restrict__ bias, float* __restrict__ C,
                           int M, int N, int K) {
  int idx = blockIdx.x * 256 + threadIdx.x;
  if (idx >= M * N) return;
  int n = idx % N, m = idx / N;
  float s = bias ? bias[n] : 0.f;
  const float* a = A + (size_t)m * K;
  const float* b = B + (size_t)n * K;
  for (int k = 0; k < K; ++k) s += a[k] * b[k];
  C[idx] = s;
}

// ---------------- naive bidirectional encoder GRU step ----------------
__global__ void enc_gru_naive(const float* __restrict__ gi_f, const float* __restrict__ gi_b,
                              const float* __restrict__ Whh_f, const float* __restrict__ bhh_f,
                              const float* __restrict__ Whh_b, const float* __restrict__ bhh_b,
                              const float* __restrict__ h_in, float* __restrict__ h_out,
                              float* __restrict__ enc_out, int s) {
  int idx = blockIdx.x * 256 + threadIdx.x;           // 2*32*512 = 32768
  if (idx >= 32768) return;
  int j = idx & 511, b = (idx >> 9) & 31, dir = idx >> 14;
  const float* gi  = dir ? gi_b  : gi_f;
  const float* Whh = dir ? Whh_b : Whh_f;
  const float* bhh = dir ? bhh_b : bhh_f;
  int t = dir ? (127 - s) : s;
  const float* h = h_in + dir * 16384 + b * 512;
  float sr = bhh[j], sz = bhh[512 + j], sn = bhh[1024 + j];
  for (int k = 0; k < 512; ++k) {
    float hv = h[k];
    sr += hv * Whh[(size_t)j * 512 + k];
    sz += hv * Whh[(size_t)(512 + j) * 512 + k];
    sn += hv * Whh[(size_t)(1024 + j) * 512 + k];
  }
  const float* g = gi + ((size_t)b * 128 + t) * 1536;
  float r = sigmoidf_(g[j] + sr);
  float z = sigmoidf_(g[512 + j] + sz);
  float n = tanhf(g[1024 + j] + r * sn);
  float hnew = (1.f - z) * n + z * h[j];
  h_out[dir * 16384 + b * 512 + j] = hnew;
  enc_out[((size_t)b * 128 + t) * 1024 + dir * 512 + j] = hnew;
}

// ---------------- naive decoder GRU step ----------------
__global__ void dec_gru_naive(const float* __restrict__ gi, const float* __restrict__ Whh,
                              const float* __restrict__ bhh,
                              const float* __restrict__ h_in, float* __restrict__ h_out) {
  int idx = blockIdx.x * 256 + threadIdx.x;           // 32*512 = 16384
  if (idx >= 16384) return;
  int j = idx & 511, b = idx >> 9;
  const float* h = h_in + b * 512;
  float sr = bhh[j], sz = bhh[512 + j], sn = bhh[1024 + j];
  for (int k = 0; k < 512; ++k) {
    float hv = h[k];
    sr += hv * Whh[(size_t)j * 512 + k];
    sz += hv * Whh[(size_t)(512 + j) * 512 + k];
    sn += hv * Whh[(size_t)(1024 + j) * 512 + k];
  }
  const float* g = gi + (size_t)b * 1536;
  float r = sigmoidf_(g[j] + sr);
  float z = sigmoidf_(g[512 + j] + sz);
  float n = tanhf(g[1024 + j] + r * sn);
  h_out[b * 512 + j] = (1.f - z) * n + z * h[j];
}

// ---------------- naive gemv with concat(src1, src2) input; one thread per (b,n) ----
__global__ void gemv_naive(const float* __restrict__ A1, const int* __restrict__ tokidx, int len1,
                           const float* __restrict__ A2, int len2,
                           const float* __restrict__ W, const float* __restrict__ bias,
                           float* __restrict__ out0, float* __restrict__ out1, int split, int N) {
  int idx = blockIdx.x * 256 + threadIdx.x;
  if (idx >= 32 * N) return;
  int n = idx % N, b = idx / N;
  const float* src1 = tokidx ? (A1 + (size_t)tokidx[b] * len1) : (A1 + (size_t)b * len1);
  const float* w = W + (size_t)n * (len1 + len2);
  float s = bias[n];
  for (int k = 0; k < len1; ++k) s += src1[k] * w[k];
  if (len2 > 0) {
    const float* a2 = A2 + (size_t)b * len2;
    for (int k = 0; k < len2; ++k) s += a2[k] * w[len1 + k];
  }
  if (n < split) out0[(size_t)b * split + n] = s;
  else out1[(size_t)b * (N - split) + (n - split)] = s;
}

// ---------------- naive attention pieces ----------------
__global__ void attn_d_naive(const float* __restrict__ h1, const float* __restrict__ Wd,
                             float* __restrict__ d) {
  int idx = blockIdx.x * 256 + threadIdx.x;           // 32*512
  if (idx >= 16384) return;
  int a = idx & 511, b = idx >> 9;
  float s = 0.f;
  const float* w = Wd + (size_t)a * 512;
  const float* h = h1 + (size_t)b * 512;
  for (int k = 0; k < 512; ++k) s += h[k] * w[k];
  d[idx] = s;
}

__global__ void attn_score_naive(const float* __restrict__ ep, const float* __restrict__ d,
                                 const float* __restrict__ v, float* __restrict__ score) {
  int idx = blockIdx.x * 256 + threadIdx.x;           // 32*128
  if (idx >= 4096) return;
  int t = idx & 127, b = idx >> 7;
  const float* e = ep + ((size_t)b * 128 + t) * 512;
  const float* dd = d + (size_t)b * 512;
  float s = 0.f;
  for (int a = 0; a < 512; ++a) s += tanhf(e[a] + dd[a]) * v[a];
  score[idx] = s;
}

__global__ void softmax_naive(float* __restrict__ score) {  // 32 rows of 128, in place
  int b = threadIdx.x;
  if (b >= 32) return;
  float* sc = score + b * 128;
  float m = sc[0];
  for (int t = 1; t < 128; ++t) m = fmaxf(m, sc[t]);
  float sum = 0.f;
  for (int t = 0; t < 128; ++t) { float e = expf(sc[t] - m); sc[t] = e; sum += e; }
  float inv = 1.f / sum;
  for (int t = 0; t < 128; ++t) sc[t] *= inv;
}

__global__ void ctx_naive(const float* __restrict__ wgt, const float* __restrict__ enc_out,
                          float* __restrict__ ctx) {
  int idx = blockIdx.x * 256 + threadIdx.x;           // 32*1024
  if (idx >= 32768) return;
  int e = idx & 1023, b = idx >> 10;
  const float* wb = wgt + b * 128;
  const float* eo = enc_out + (size_t)b * 131072 + e;
  float s = 0.f;
  for (int t = 0; t < 128; ++t) s += wb[t] * eo[(size_t)t * 1024];
  ctx[idx] = s;
}

// ---------------- naive argmax (first max, matches np.argmax) ----------------
__global__ void argmax_naive(const float* __restrict__ logits, int* __restrict__ tok,
                             int* __restrict__ decoded, int step) {
  int b = threadIdx.x;
  if (b >= 32) return;
  const float* L = logits + (size_t)b * 8000;
  float best = L[0];
  int bi = 0;
  for (int v = 1; v < 8000; ++v) {
    if (L[v] > best) { best = L[v]; bi = v; }
  }
  tok[b] = bi;
  decoded[b * 50 + step + 1] = bi;
}

__global__ void init_kernel(int* __restrict__ tok, int* __restrict__ decoded) {
  int b = threadIdx.x;
  if (b >= 32) return;
  tok[b] = 1;
  decoded[b * 50] = 1;
}

__global__ void zero_kernel(float* __restrict__ p, int n) {
  int i = blockIdx.x * 256 + threadIdx.x;
  if (i < n) p[i] = 0.f;
}

__global__ void fill_int_kernel(int* __restrict__ p, int n, int val) {
  int i = blockIdx.x * 256 + threadIdx.x;
  if (i < n) p[i] = val;
}

extern "C" void kernel_launch(void* const* d_in, const int* in_sizes, int n_in,
                              void* d_out, int out_size, void* d_ws, size_t ws_size,
                              hipStream_t stream) {
  int* decoded = (int*)d_out;

  // ---- interface validation: sentinel-fill output on any mismatch ----
  static const int kExp[29] = {
      4194304, 655360, 512, 1310720, 512,
      786432, 786432, 1536, 1536, 786432, 786432, 1536, 1536,
      1048576, 1024, 4096000, 524288, 262144, 512,
      2359296, 786432, 1536, 1536, 786432, 786432, 1536, 1536,
      12288000, 8000};
  int diag = 0;
  if (n_in != 29) diag = 29000;
  else {
    for (int i = 0; i < 29; ++i)
      if (in_sizes[i] != kExp[i]) { diag = 20000 + i * 100; break; }
  }
  if (!diag && out_size != 1600) diag = 19000;
  if (diag) {
    fill_int_kernel<<<(out_size + 255) / 256, 256, 0, stream>>>(decoded, out_size, diag);
    return;
  }

  const float* features  = (const float*)d_in[0];
  const float* conv_w1   = (const float*)d_in[1];
  const float* conv_b1   = (const float*)d_in[2];
  const float* conv_w2   = (const float*)d_in[3];
  const float* conv_b2   = (const float*)d_in[4];
  const float* enc_Wih_f = (const float*)d_in[5];
  const float* enc_Whh_f = (const float*)d_in[6];
  const float* enc_bih_f = (const float*)d_in[7];
  const float* enc_bhh_f = (const float*)d_in[8];
  const float* enc_Wih_b = (const float*)d_in[9];
  const float* enc_Whh_b = (const float*)d_in[10];
  const float* enc_bih_b = (const float*)d_in[11];
  const float* enc_bhh_b = (const float*)d_in[12];
  const float* bridge_W  = (const float*)d_in[13];
  const float* bridge_b  = (const float*)d_in[14];
  const float* emb       = (const float*)d_in[15];
  const float* attn_We   = (const float*)d_in[16];
  const float* attn_Wd   = (const float*)d_in[17];
  const float* attn_v    = (const float*)d_in[18];
  const float* dec_Wih0  = (const float*)d_in[19];
  const float* dec_Whh0  = (const float*)d_in[20];
  const float* dec_bih0  = (const float*)d_in[21];
  const float* dec_bhh0  = (const float*)d_in[22];
  const float* dec_Wih1  = (const float*)d_in[23];
  const float* dec_Whh1  = (const float*)d_in[24];
  const float* dec_bih1  = (const float*)d_in[25];
  const float* dec_bhh1  = (const float*)d_in[26];
  const float* proj_W    = (const float*)d_in[27];
  const float* proj_b    = (const float*)d_in[28];

  // ---- static workspace ----
  float* ws = nullptr;
  hipGetSymbolAddress((void**)&ws, HIP_SYMBOL(g_ws));
  float* score   = ws;                    //      4,096 (32x128)
  float* dbuf    = ws + 4096;             //     16,384 (32x512)
  float* y1      = ws + 10485760;         //  4,194,304
  float* x2      = ws + 14680064;         //  2,097,152
  float* gi_f    = ws + 16777216;         //  6,291,456
  float* gi_b    = ws + 23068672;         //  6,291,456
  float* enc_out = ws + 29360128;         //  4,194,304
  float* enc_pj  = ws + 33554432;         //  2,097,152
  float* h_enc   = ws + 35651584;         //     65,536 (2 bufs x 2 dir x 32 x 512)
  float* h0d     = ws + 35717120;         //     32,768
  float* h1d     = ws + 35749888;         //     32,768
  float* ctxb    = ws + 35782656;         //     32,768
  float* gi0     = ws + 35815424;         //     49,152
  float* gi1     = ws + 35864576;         //     49,152
  float* logits  = ws + 35913728;         //    256,000
  int*   tok     = (int*)(ws + 36169728); //         32

  // ---- convs (direct, naive) ----
  conv1_naive<<<16384, 256, 0, stream>>>(features, conv_w1, conv_b1, y1);
  conv2_naive<<<8192, 256, 0, stream>>>(y1, conv_w2, conv_b2, x2);

  // ---- GRU input transforms ----
  gemm_naive<<<24576, 256, 0, stream>>>(x2, enc_Wih_f, enc_bih_f, gi_f, 4096, 1536, 512);
  gemm_naive<<<24576, 256, 0, stream>>>(x2, enc_Wih_b, enc_bih_b, gi_b, 4096, 1536, 512);

  // ---- bidirectional encoder recurrence ----
  zero_kernel<<<256, 256, 0, stream>>>(h_enc, 65536);
  for (int s = 0; s < 128; ++s) {
    enc_gru_naive<<<128, 256, 0, stream>>>(gi_f, gi_b,
        enc_Whh_f, enc_bhh_f, enc_Whh_b, enc_bhh_b,
        h_enc + (s & 1) * 32768, h_enc + ((s + 1) & 1) * 32768, enc_out, s);
  }
  float* h_fin = h_enc;  // final state in buffer 0 after 128 steps

  // ---- bridge ----
  gemv_naive<<<128, 256, 0, stream>>>(h_fin, nullptr, 512, h_fin + 16384, 512,
      bridge_W, bridge_b, h0d, h1d, 512, 1024);

  // ---- enc_proj ----
  gemm_naive<<<8192, 256, 0, stream>>>(enc_out, attn_We, nullptr, enc_pj, 4096, 512, 1024);

  init_kernel<<<1, 64, 0, stream>>>(tok, decoded);

  // ---- greedy attention decoder, 49 steps ----
  for (int s = 0; s < 49; ++s) {
    int cur = s & 1, nxt = (s + 1) & 1;
    attn_d_naive<<<64, 256, 0, stream>>>(h1d + cur * 16384, attn_Wd, dbuf);
    attn_score_naive<<<16, 256, 0, stream>>>(enc_pj, dbuf, attn_v, score);
    softmax_naive<<<1, 64, 0, stream>>>(score);
    ctx_naive<<<128, 256, 0, stream>>>(score, enc_out, ctxb);
    gemv_naive<<<192, 256, 0, stream>>>(emb, tok, 512, ctxb, 1024,
        dec_Wih0, dec_bih0, gi0, nullptr, 1536, 1536);
    dec_gru_naive<<<64, 256, 0, stream>>>(gi0, dec_Whh0, dec_bhh0,
        h0d + cur * 16384, h0d + nxt * 16384);
    gemv_naive<<<192, 256, 0, stream>>>(h0d + nxt * 16384, nullptr, 512, nullptr, 0,
        dec_Wih1, dec_bih1, gi1, nullptr, 1536, 1536);
    dec_gru_naive<<<64, 256, 0, stream>>>(gi1, dec_Whh1, dec_bhh1,
        h1d + cur * 16384, h1d + nxt * 16384);
    gemv_naive<<<1000, 256, 0, stream>>>(h1d + nxt * 16384, nullptr, 512, ctxb, 1024,
        proj_W, proj_b, logits, nullptr, 8000, 8000);
    argmax_naive<<<1, 64, 0, stream>>>(logits, tok, decoded, s);
  }
}

// Round 4
// 44844.427 us; speedup vs baseline: 4.2445x; 4.2445x over previous
//
#include <hip/hip_runtime.h>
#include <math.h>

#define DINLINE __device__ __forceinline__

DINLINE float sigmoidf_(float x) { return 1.f / (1.f + expf(-x)); }

// All scratch in static device memory — independent of ws_size (verified graph-safe in R3).
__device__ __align__(256) float g_ws[36200000];

// ---------------- im2col for the two convs ----------------
// P1: rows m = b*256 + l (8192), cols = c*5 + k (1280); input features (32,512,256) [b][pos][c]
__global__ void im2col1_kernel(const float* __restrict__ feat, float* __restrict__ P) {
  size_t i = (size_t)blockIdx.x * 256 + threadIdx.x;
  int col = (int)(i % 1280);
  int row = (int)(i / 1280);
  int c = col / 5, k = col - c * 5;
  int l = row & 255, b = row >> 8;
  int pos = 2 * l + k - 2;
  P[i] = (pos >= 0 && pos < 512) ? feat[((size_t)b * 512 + pos) * 256 + c] : 0.f;
}

// P2: rows m = b*128 + l (4096), cols = c*5 + k (2560); input y1 (32,256,512) [b][pos][c]
__global__ void im2col2_kernel(const float* __restrict__ y1, float* __restrict__ P) {
  size_t i = (size_t)blockIdx.x * 256 + threadIdx.x;
  int col = (int)(i % 2560);
  int row = (int)(i / 2560);
  int c = col / 5, k = col - c * 5;
  int l = row & 127, b = row >> 7;
  int pos = 2 * l + k - 2;
  P[i] = (pos >= 0 && pos < 256) ? y1[((size_t)b * 256 + pos) * 512 + c] : 0.f;
}

// ---------------- fp32 tiled GEMM: C[m,n] = sum_k A[m,k]*B[n,k] + bias[n], opt relu ----
__global__ __launch_bounds__(256) void sgemm128(
    const float* __restrict__ A, const float* __restrict__ B,
    const float* __restrict__ bias, float* __restrict__ C,
    int M, int N, int K, int relu) {
  __shared__ float As[8][132];
  __shared__ float Bs[8][132];
  int bm = blockIdx.y * 128, bn = blockIdx.x * 128;
  int tid = threadIdx.x;
  int tx = tid & 15, ty = tid >> 4;
  float acc[8][8];
#pragma unroll
  for (int i = 0; i < 8; ++i)
#pragma unroll
    for (int j = 0; j < 8; ++j) acc[i][j] = 0.f;
  int lr = tid >> 1;
  int lc = (tid & 1) * 4;
  const float* Arow = A + (size_t)(bm + lr) * K + lc;
  const float* Brow = B + (size_t)(bn + lr) * K + lc;
  for (int k0 = 0; k0 < K; k0 += 8) {
    float4 av = *(const float4*)(Arow + k0);
    float4 bv = *(const float4*)(Brow + k0);
    As[lc + 0][lr] = av.x; As[lc + 1][lr] = av.y; As[lc + 2][lr] = av.z; As[lc + 3][lr] = av.w;
    Bs[lc + 0][lr] = bv.x; Bs[lc + 1][lr] = bv.y; Bs[lc + 2][lr] = bv.z; Bs[lc + 3][lr] = bv.w;
    __syncthreads();
#pragma unroll
    for (int kk = 0; kk < 8; ++kk) {
      float4 a0 = *(const float4*)&As[kk][ty * 8];
      float4 a1 = *(const float4*)&As[kk][ty * 8 + 4];
      float4 b0 = *(const float4*)&Bs[kk][tx * 8];
      float4 b1 = *(const float4*)&Bs[kk][tx * 8 + 4];
      float aa[8] = {a0.x, a0.y, a0.z, a0.w, a1.x, a1.y, a1.z, a1.w};
      float bb[8] = {b0.x, b0.y, b0.z, b0.w, b1.x, b1.y, b1.z, b1.w};
#pragma unroll
      for (int i = 0; i < 8; ++i)
#pragma unroll
        for (int j = 0; j < 8; ++j) acc[i][j] += aa[i] * bb[j];
    }
    __syncthreads();
  }
#pragma unroll
  for (int i = 0; i < 8; ++i) {
    int m = bm + ty * 8 + i;
#pragma unroll
    for (int j = 0; j < 8; ++j) {
      int n = bn + tx * 8 + j;
      float v = acc[i][j] + (bias ? bias[n] : 0.f);
      if (relu) v = fmaxf(v, 0.f);
      C[(size_t)m * N + n] = v;
    }
  }
}

// ---------------- fused bidirectional encoder GRU step ----------------
// FIXED (R3 root cause): h staged as float4 hs4[32*128] (exactly 64KB, NO row overlap);
// XOR swizzle (kf ^ (b&7)) on the float4 index breaks the 2048B-stride bank conflict.
__global__ __launch_bounds__(256) void enc_gru_step(
    const float* __restrict__ gi_f, const float* __restrict__ gi_b,
    const float* __restrict__ Whh_f, const float* __restrict__ bhh_f,
    const float* __restrict__ Whh_b, const float* __restrict__ bhh_b,
    const float* __restrict__ h_in, float* __restrict__ h_out,
    float* __restrict__ enc_out, int s) {
  int dir = blockIdx.x >> 6;
  int j = ((blockIdx.x & 63) << 3) + (threadIdx.x >> 5);
  int b = threadIdx.x & 31;
  __shared__ float4 hs4[32 * 128];  // [row b][swizzled kf]
  const float4* hbase = (const float4*)(h_in + dir * 32 * 512);
  for (int i = threadIdx.x; i < 32 * 128; i += 256) {
    int bb = i >> 7, kf = i & 127;
    hs4[bb * 128 + (kf ^ (bb & 7))] = hbase[i];
  }
  __syncthreads();
  const float* gi = dir ? gi_b : gi_f;
  const float* Whh = dir ? Whh_b : Whh_f;
  const float* bhh = dir ? bhh_b : bhh_f;
  int t = dir ? (127 - s) : s;
  const float4* wr = (const float4*)(Whh + (size_t)j * 512);
  const float4* wz = (const float4*)(Whh + (size_t)(512 + j) * 512);
  const float4* wn = (const float4*)(Whh + (size_t)(1024 + j) * 512);
  const float4* hrow = hs4 + b * 128;
  int sw = b & 7;
  float sr = 0.f, sz = 0.f, sn = 0.f;
#pragma unroll 4
  for (int kf = 0; kf < 128; ++kf) {
    float4 hv = hrow[kf ^ sw];
    float4 r4 = wr[kf];
    float4 z4 = wz[kf];
    float4 n4 = wn[kf];
    sr += hv.x * r4.x + hv.y * r4.y + hv.z * r4.z + hv.w * r4.w;
    sz += hv.x * z4.x + hv.y * z4.y + hv.z * z4.z + hv.w * z4.w;
    sn += hv.x * n4.x + hv.y * n4.y + hv.z * n4.z + hv.w * n4.w;
  }
  const float* g = gi + ((size_t)b * 128 + t) * 1536;
  float r = sigmoidf_(g[j] + sr + bhh[j]);
  float z = sigmoidf_(g[512 + j] + sz + bhh[512 + j]);
  float n = tanhf(g[1024 + j] + r * (sn + bhh[1024 + j]));
  float4 hj4 = hrow[(j >> 2) ^ sw];
  float hj = ((const float*)&hj4)[j & 3];
  float hnew = (1.f - z) * n + z * hj;
  h_out[dir * 32 * 512 + b * 512 + j] = hnew;
  enc_out[((size_t)b * 128 + t) * 1024 + dir * 512 + j] = hnew;
}

// ---------------- decoder GRU step (same swizzled-LDS fix) ----------------
__global__ __launch_bounds__(256) void dec_gru_step(
    const float* __restrict__ gi, const float* __restrict__ Whh,
    const float* __restrict__ bhh,
    const float* __restrict__ h_in, float* __restrict__ h_out) {
  int j = (blockIdx.x << 3) + (threadIdx.x >> 5);
  int b = threadIdx.x & 31;
  __shared__ float4 hs4[32 * 128];
  const float4* hbase = (const float4*)h_in;
  for (int i = threadIdx.x; i < 32 * 128; i += 256) {
    int bb = i >> 7, kf = i & 127;
    hs4[bb * 128 + (kf ^ (bb & 7))] = hbase[i];
  }
  __syncthreads();
  const float4* wr = (const float4*)(Whh + (size_t)j * 512);
  const float4* wz = (const float4*)(Whh + (size_t)(512 + j) * 512);
  const float4* wn = (const float4*)(Whh + (size_t)(1024 + j) * 512);
  const float4* hrow = hs4 + b * 128;
  int sw = b & 7;
  float sr = 0.f, sz = 0.f, sn = 0.f;
#pragma unroll 4
  for (int kf = 0; kf < 128; ++kf) {
    float4 hv = hrow[kf ^ sw];
    float4 r4 = wr[kf];
    float4 z4 = wz[kf];
    float4 n4 = wn[kf];
    sr += hv.x * r4.x + hv.y * r4.y + hv.z * r4.z + hv.w * r4.w;
    sz += hv.x * z4.x + hv.y * z4.y + hv.z * z4.z + hv.w * z4.w;
    sn += hv.x * n4.x + hv.y * n4.y + hv.z * n4.z + hv.w * n4.w;
  }
  const float* g = gi + (size_t)b * 1536;
  float r = sigmoidf_(g[j] + sr + bhh[j]);
  float z = sigmoidf_(g[512 + j] + sz + bhh[512 + j]);
  float n = tanhf(g[1024 + j] + r * (sn + bhh[1024 + j]));
  float4 hj4 = hrow[(j >> 2) ^ sw];
  float hj = ((const float*)&hj4)[j & 3];
  h_out[b * 512 + j] = (1.f - z) * n + z * hj;
}

// ---------------- batched GEMV, 4 output rows per thread ----------------
__global__ __launch_bounds__(256) void gemv4_kernel(
    const float* __restrict__ A1, const int* __restrict__ tokidx, int len1,
    const float* __restrict__ A2, int len2,
    const float* __restrict__ W, const float* __restrict__ bias,
    float* __restrict__ out0, float* __restrict__ out1, int split, int N) {
  int b = blockIdx.y;
  int tid = threadIdx.x;
  __shared__ float a[1536];
  const float* src1 = tokidx ? (A1 + (size_t)tokidx[b] * len1) : (A1 + (size_t)b * len1);
  for (int i = tid; i < len1; i += 256) a[i] = src1[i];
  for (int i = tid; i < len2; i += 256) a[len1 + i] = A2[(size_t)b * len2 + i];
  __syncthreads();
  int K = len1 + len2;
  int n0 = (blockIdx.x * 256 + tid) * 4;
  if (n0 >= N) return;
  const float* w0 = W + (size_t)n0 * K;
  const float* w1 = w0 + K;
  const float* w2 = w1 + K;
  const float* w3 = w2 + K;
  float s0 = 0.f, s1 = 0.f, s2 = 0.f, s3 = 0.f;
  for (int k = 0; k < K; k += 4) {
    float4 av = *(const float4*)&a[k];
    float4 x0 = *(const float4*)&w0[k];
    float4 x1 = *(const float4*)&w1[k];
    float4 x2 = *(const float4*)&w2[k];
    float4 x3 = *(const float4*)&w3[k];
    s0 += av.x * x0.x + av.y * x0.y + av.z * x0.z + av.w * x0.w;
    s1 += av.x * x1.x + av.y * x1.y + av.z * x1.z + av.w * x1.w;
    s2 += av.x * x2.x + av.y * x2.y + av.z * x2.z + av.w * x2.w;
    s3 += av.x * x3.x + av.y * x3.y + av.z * x3.z + av.w * x3.w;
  }
  float rv[4] = {s0, s1, s2, s3};
#pragma unroll
  for (int q = 0; q < 4; ++q) {
    int n = n0 + q;
    float val = rv[q] + bias[n];
    if (n < split) out0[(size_t)b * split + n] = val;
    else out1[(size_t)b * (N - split) + (n - split)] = val;
  }
}

// ---------------- fused attention (one block per batch element) ----------------
__global__ __launch_bounds__(512) void attention_kernel(
    const float* __restrict__ h1,
    const float* __restrict__ Wd,
    const float* __restrict__ v,
    const float* __restrict__ enc_proj,
    const float* __restrict__ enc_out,
    float* __restrict__ ctx) {
  int b = blockIdx.x;
  int tid = threadIdx.x;
  __shared__ float hs[512];
  __shared__ float d[512];
  __shared__ float red[512];
  __shared__ float sc[128];
  hs[tid] = h1[b * 512 + tid];
  __syncthreads();
  {
    const float* w = Wd + (size_t)tid * 512;
    float s = 0.f;
    for (int k = 0; k < 512; k += 4) {
      float4 wv = *(const float4*)&w[k];
      float4 hv = *(const float4*)&hs[k];
      s += hv.x * wv.x + hv.y * wv.y + hv.z * wv.z + hv.w * wv.w;
    }
    d[tid] = s;
  }
  __syncthreads();
  {
    int t = tid >> 2, part = tid & 3;
    const float* ep = enc_proj + ((size_t)b * 128 + t) * 512 + part * 128;
    const float* dd = d + part * 128;
    const float* vv = v + part * 128;
    float s = 0.f;
    for (int a = 0; a < 128; ++a) s += tanhf(ep[a] + dd[a]) * vv[a];
    red[tid] = s;
  }
  __syncthreads();
  if (tid < 128) sc[tid] = red[tid * 4] + red[tid * 4 + 1] + red[tid * 4 + 2] + red[tid * 4 + 3];
  __syncthreads();
  if (tid == 0) {
    float m = -1e30f;
    for (int t = 0; t < 128; ++t) m = fmaxf(m, sc[t]);
    float sum = 0.f;
    for (int t = 0; t < 128; ++t) { float e = expf(sc[t] - m); sc[t] = e; sum += e; }
    float inv = 1.f / sum;
    for (int t = 0; t < 128; ++t) sc[t] *= inv;
  }
  __syncthreads();
  for (int e = tid; e < 1024; e += 512) {
    const float* eo = enc_out + (size_t)b * 131072 + e;
    float s = 0.f;
    for (int t = 0; t < 128; ++t) s += sc[t] * eo[(size_t)t * 1024];
    ctx[b * 1024 + e] = s;
  }
}

// ---------------- argmax (first-max tie-break, matches np.argmax) ----------------
__global__ __launch_bounds__(256) void argmax_kernel(
    const float* __restrict__ logits, int* __restrict__ tok,
    int* __restrict__ decoded, int step) {
  int b = blockIdx.x, tid = threadIdx.x;
  __shared__ float bv[256];
  __shared__ int bi[256];
  float best = -3.4e38f;
  int bidx = 0x7fffffff;
  const float* L = logits + (size_t)b * 8000;
  for (int v = tid; v < 8000; v += 256) {
    float x = L[v];
    if (x > best) { best = x; bidx = v; }
  }
  bv[tid] = best; bi[tid] = bidx;
  __syncthreads();
  for (int s = 128; s > 0; s >>= 1) {
    if (tid < s) {
      if (bv[tid + s] > bv[tid] || (bv[tid + s] == bv[tid] && bi[tid + s] < bi[tid])) {
        bv[tid] = bv[tid + s];
        bi[tid] = bi[tid + s];
      }
    }
    __syncthreads();
  }
  if (tid == 0) { tok[b] = bi[0]; decoded[b * 50 + step + 1] = bi[0]; }
}

__global__ void init_kernel(int* __restrict__ tok, int* __restrict__ decoded) {
  int b = threadIdx.x;
  if (b >= 32) return;
  tok[b] = 1;
  decoded[b * 50] = 1;
}

__global__ void zero_kernel(float* __restrict__ p, int n) {
  int i = blockIdx.x * 256 + threadIdx.x;
  if (i < n) p[i] = 0.f;
}

extern "C" void kernel_launch(void* const* d_in, const int* in_sizes, int n_in,
                              void* d_out, int out_size, void* d_ws, size_t ws_size,
                              hipStream_t stream) {
  const float* features  = (const float*)d_in[0];
  const float* conv_w1   = (const float*)d_in[1];
  const float* conv_b1   = (const float*)d_in[2];
  const float* conv_w2   = (const float*)d_in[3];
  const float* conv_b2   = (const float*)d_in[4];
  const float* enc_Wih_f = (const float*)d_in[5];
  const float* enc_Whh_f = (const float*)d_in[6];
  const float* enc_bih_f = (const float*)d_in[7];
  const float* enc_bhh_f = (const float*)d_in[8];
  const float* enc_Wih_b = (const float*)d_in[9];
  const float* enc_Whh_b = (const float*)d_in[10];
  const float* enc_bih_b = (const float*)d_in[11];
  const float* enc_bhh_b = (const float*)d_in[12];
  const float* bridge_W  = (const float*)d_in[13];
  const float* bridge_b  = (const float*)d_in[14];
  const float* emb       = (const float*)d_in[15];
  const float* attn_We   = (const float*)d_in[16];
  const float* attn_Wd   = (const float*)d_in[17];
  const float* attn_v    = (const float*)d_in[18];
  const float* dec_Wih0  = (const float*)d_in[19];
  const float* dec_Whh0  = (const float*)d_in[20];
  const float* dec_bih0  = (const float*)d_in[21];
  const float* dec_bhh0  = (const float*)d_in[22];
  const float* dec_Wih1  = (const float*)d_in[23];
  const float* dec_Whh1  = (const float*)d_in[24];
  const float* dec_bih1  = (const float*)d_in[25];
  const float* dec_bhh1  = (const float*)d_in[26];
  const float* proj_W    = (const float*)d_in[27];
  const float* proj_b    = (const float*)d_in[28];
  int* decoded = (int*)d_out;

  // ---- static workspace (non-overlapping layout; same as verified R3 run) ----
  float* ws = nullptr;
  hipGetSymbolAddress((void**)&ws, HIP_SYMBOL(g_ws));
  float* P       = ws;                    // 10,485,760
  float* y1      = ws + 10485760;         //  4,194,304
  float* x2      = ws + 14680064;         //  2,097,152
  float* gi_f    = ws + 16777216;         //  6,291,456
  float* gi_b    = ws + 23068672;         //  6,291,456
  float* enc_out = ws + 29360128;         //  4,194,304
  float* enc_pj  = ws + 33554432;         //  2,097,152
  float* h_enc   = ws + 35651584;         //     65,536 (2 bufs x 2 dir x 32 x 512)
  float* h0d     = ws + 35717120;         //     32,768
  float* h1d     = ws + 35749888;         //     32,768
  float* ctxb    = ws + 35782656;         //     32,768
  float* gi0     = ws + 35815424;         //     49,152
  float* gi1     = ws + 35864576;         //     49,152
  float* logits  = ws + 35913728;         //    256,000
  int*   tok     = (int*)(ws + 36169728); //         32

  // ---- conv front-end as im2col + GEMM (+bias+relu) ----
  im2col1_kernel<<<40960, 256, 0, stream>>>(features, P);
  sgemm128<<<dim3(4, 64), 256, 0, stream>>>(P, conv_w1, conv_b1, y1, 8192, 512, 1280, 1);
  im2col2_kernel<<<40960, 256, 0, stream>>>(y1, P);
  sgemm128<<<dim3(4, 32), 256, 0, stream>>>(P, conv_w2, conv_b2, x2, 4096, 512, 2560, 1);

  // ---- GRU input transforms ----
  sgemm128<<<dim3(12, 32), 256, 0, stream>>>(x2, enc_Wih_f, enc_bih_f, gi_f, 4096, 1536, 512, 0);
  sgemm128<<<dim3(12, 32), 256, 0, stream>>>(x2, enc_Wih_b, enc_bih_b, gi_b, 4096, 1536, 512, 0);

  // ---- bidirectional encoder recurrence ----
  zero_kernel<<<256, 256, 0, stream>>>(h_enc, 65536);
  for (int s = 0; s < 128; ++s) {
    enc_gru_step<<<128, 256, 0, stream>>>(gi_f, gi_b,
        enc_Whh_f, enc_bhh_f, enc_Whh_b, enc_bhh_b,
        h_enc + (s & 1) * 32768, h_enc + ((s + 1) & 1) * 32768, enc_out, s);
  }
  float* h_fin = h_enc;  // final state in buffer 0 after 128 steps

  // ---- bridge ----
  gemv4_kernel<<<dim3(1, 32), 256, 0, stream>>>(h_fin, nullptr, 512, h_fin + 16384, 512,
      bridge_W, bridge_b, h0d, h1d, 512, 1024);

  // ---- enc_proj ----
  sgemm128<<<dim3(4, 32), 256, 0, stream>>>(enc_out, attn_We, nullptr, enc_pj, 4096, 512, 1024, 0);

  init_kernel<<<1, 64, 0, stream>>>(tok, decoded);

  // ---- greedy attention decoder, 49 steps ----
  for (int s = 0; s < 49; ++s) {
    int cur = s & 1, nxt = (s + 1) & 1;
    attention_kernel<<<32, 512, 0, stream>>>(h1d + cur * 16384, attn_Wd, attn_v,
                                             enc_pj, enc_out, ctxb);
    gemv4_kernel<<<dim3(2, 32), 256, 0, stream>>>(emb, tok, 512, ctxb, 1024,
        dec_Wih0, dec_bih0, gi0, nullptr, 1536, 1536);
    dec_gru_step<<<64, 256, 0, stream>>>(gi0, dec_Whh0, dec_bhh0,
        h0d + cur * 16384, h0d + nxt * 16384);
    gemv4_kernel<<<dim3(2, 32), 256, 0, stream>>>(h0d + nxt * 16384, nullptr, 512, nullptr, 0,
        dec_Wih1, dec_bih1, gi1, nullptr, 1536, 1536);
    dec_gru_step<<<64, 256, 0, stream>>>(gi1, dec_Whh1, dec_bhh1,
        h1d + cur * 16384, h1d + nxt * 16384);
    gemv4_kernel<<<dim3(8, 32), 256, 0, stream>>>(h1d + nxt * 16384, nullptr, 512, ctxb, 1024,
        proj_W, proj_b, logits, nullptr, 8000, 8000);
    argmax_kernel<<<32, 256, 0, stream>>>(logits, tok, decoded, s);
  }
}

// Round 5
// 18912.810 us; speedup vs baseline: 10.0642x; 2.3711x over previous
//
#include <hip/hip_runtime.h>
#include <math.h>

#define DINLINE __device__ __forceinline__

DINLINE float sigmoidf_(float x) { return 1.f / (1.f + expf(-x)); }

// All scratch in static device memory — independent of ws_size (verified graph-safe in R3/R4).
__device__ __align__(256) float g_ws[36200000];

// ---------------- im2col for the two convs ----------------
__global__ void im2col1_kernel(const float* __restrict__ feat, float* __restrict__ P) {
  size_t i = (size_t)blockIdx.x * 256 + threadIdx.x;
  int col = (int)(i % 1280);
  int row = (int)(i / 1280);
  int c = col / 5, k = col - c * 5;
  int l = row & 255, b = row >> 8;
  int pos = 2 * l + k - 2;
  P[i] = (pos >= 0 && pos < 512) ? feat[((size_t)b * 512 + pos) * 256 + c] : 0.f;
}

__global__ void im2col2_kernel(const float* __restrict__ y1, float* __restrict__ P) {
  size_t i = (size_t)blockIdx.x * 256 + threadIdx.x;
  int col = (int)(i % 2560);
  int row = (int)(i / 2560);
  int c = col / 5, k = col - c * 5;
  int l = row & 127, b = row >> 7;
  int pos = 2 * l + k - 2;
  P[i] = (pos >= 0 && pos < 256) ? y1[((size_t)b * 256 + pos) * 512 + c] : 0.f;
}

// ---------------- fp32 tiled GEMM: C[m,n] = sum_k A[m,k]*B[n,k] + bias[n], opt relu ----
__global__ __launch_bounds__(256) void sgemm128(
    const float* __restrict__ A, const float* __restrict__ B,
    const float* __restrict__ bias, float* __restrict__ C,
    int M, int N, int K, int relu) {
  __shared__ float As[8][132];
  __shared__ float Bs[8][132];
  int bm = blockIdx.y * 128, bn = blockIdx.x * 128;
  int tid = threadIdx.x;
  int tx = tid & 15, ty = tid >> 4;
  float acc[8][8];
#pragma unroll
  for (int i = 0; i < 8; ++i)
#pragma unroll
    for (int j = 0; j < 8; ++j) acc[i][j] = 0.f;
  int lr = tid >> 1;
  int lc = (tid & 1) * 4;
  const float* Arow = A + (size_t)(bm + lr) * K + lc;
  const float* Brow = B + (size_t)(bn + lr) * K + lc;
  for (int k0 = 0; k0 < K; k0 += 8) {
    float4 av = *(const float4*)(Arow + k0);
    float4 bv = *(const float4*)(Brow + k0);
    As[lc + 0][lr] = av.x; As[lc + 1][lr] = av.y; As[lc + 2][lr] = av.z; As[lc + 3][lr] = av.w;
    Bs[lc + 0][lr] = bv.x; Bs[lc + 1][lr] = bv.y; Bs[lc + 2][lr] = bv.z; Bs[lc + 3][lr] = bv.w;
    __syncthreads();
#pragma unroll
    for (int kk = 0; kk < 8; ++kk) {
      float4 a0 = *(const float4*)&As[kk][ty * 8];
      float4 a1 = *(const float4*)&As[kk][ty * 8 + 4];
      float4 b0 = *(const float4*)&Bs[kk][tx * 8];
      float4 b1 = *(const float4*)&Bs[kk][tx * 8 + 4];
      float aa[8] = {a0.x, a0.y, a0.z, a0.w, a1.x, a1.y, a1.z, a1.w};
      float bb[8] = {b0.x, b0.y, b0.z, b0.w, b1.x, b1.y, b1.z, b1.w};
#pragma unroll
      for (int i = 0; i < 8; ++i)
#pragma unroll
        for (int j = 0; j < 8; ++j) acc[i][j] += aa[i] * bb[j];
    }
    __syncthreads();
  }
#pragma unroll
  for (int i = 0; i < 8; ++i) {
    int m = bm + ty * 8 + i;
#pragma unroll
    for (int j = 0; j < 8; ++j) {
      int n = bn + tx * 8 + j;
      float v = acc[i][j] + (bias ? bias[n] : 0.f);
      if (relu) v = fmaxf(v, 0.f);
      C[(size_t)m * N + n] = v;
    }
  }
}

// ---------------- fused bidirectional encoder GRU step (R4-verified) ----------------
__global__ __launch_bounds__(256) void enc_gru_step(
    const float* __restrict__ gi_f, const float* __restrict__ gi_b,
    const float* __restrict__ Whh_f, const float* __restrict__ bhh_f,
    const float* __restrict__ Whh_b, const float* __restrict__ bhh_b,
    const float* __restrict__ h_in, float* __restrict__ h_out,
    float* __restrict__ enc_out, int s) {
  int dir = blockIdx.x >> 6;
  int j = ((blockIdx.x & 63) << 3) + (threadIdx.x >> 5);
  int b = threadIdx.x & 31;
  __shared__ float4 hs4[32 * 128];
  const float4* hbase = (const float4*)(h_in + dir * 32 * 512);
  for (int i = threadIdx.x; i < 32 * 128; i += 256) {
    int bb = i >> 7, kf = i & 127;
    hs4[bb * 128 + (kf ^ (bb & 7))] = hbase[i];
  }
  __syncthreads();
  const float* gi = dir ? gi_b : gi_f;
  const float* Whh = dir ? Whh_b : Whh_f;
  const float* bhh = dir ? bhh_b : bhh_f;
  int t = dir ? (127 - s) : s;
  const float4* wr = (const float4*)(Whh + (size_t)j * 512);
  const float4* wz = (const float4*)(Whh + (size_t)(512 + j) * 512);
  const float4* wn = (const float4*)(Whh + (size_t)(1024 + j) * 512);
  const float4* hrow = hs4 + b * 128;
  int sw = b & 7;
  float sr = 0.f, sz = 0.f, sn = 0.f;
#pragma unroll 4
  for (int kf = 0; kf < 128; ++kf) {
    float4 hv = hrow[kf ^ sw];
    float4 r4 = wr[kf];
    float4 z4 = wz[kf];
    float4 n4 = wn[kf];
    sr += hv.x * r4.x + hv.y * r4.y + hv.z * r4.z + hv.w * r4.w;
    sz += hv.x * z4.x + hv.y * z4.y + hv.z * z4.z + hv.w * z4.w;
    sn += hv.x * n4.x + hv.y * n4.y + hv.z * n4.z + hv.w * n4.w;
  }
  const float* g = gi + ((size_t)b * 128 + t) * 1536;
  float r = sigmoidf_(g[j] + sr + bhh[j]);
  float z = sigmoidf_(g[512 + j] + sz + bhh[512 + j]);
  float n = tanhf(g[1024 + j] + r * (sn + bhh[1024 + j]));
  float4 hj4 = hrow[(j >> 2) ^ sw];
  float hj = ((const float*)&hj4)[j & 3];
  float hnew = (1.f - z) * n + z * hj;
  h_out[dir * 32 * 512 + b * 512 + j] = hnew;
  enc_out[((size_t)b * 128 + t) * 1024 + dir * 512 + j] = hnew;
}

// ---------------- decoder GRU step (R4-verified) ----------------
__global__ __launch_bounds__(256) void dec_gru_step(
    const float* __restrict__ gi, const float* __restrict__ Whh,
    const float* __restrict__ bhh,
    const float* __restrict__ h_in, float* __restrict__ h_out) {
  int j = (blockIdx.x << 3) + (threadIdx.x >> 5);
  int b = threadIdx.x & 31;
  __shared__ float4 hs4[32 * 128];
  const float4* hbase = (const float4*)h_in;
  for (int i = threadIdx.x; i < 32 * 128; i += 256) {
    int bb = i >> 7, kf = i & 127;
    hs4[bb * 128 + (kf ^ (bb & 7))] = hbase[i];
  }
  __syncthreads();
  const float4* wr = (const float4*)(Whh + (size_t)j * 512);
  const float4* wz = (const float4*)(Whh + (size_t)(512 + j) * 512);
  const float4* wn = (const float4*)(Whh + (size_t)(1024 + j) * 512);
  const float4* hrow = hs4 + b * 128;
  int sw = b & 7;
  float sr = 0.f, sz = 0.f, sn = 0.f;
#pragma unroll 4
  for (int kf = 0; kf < 128; ++kf) {
    float4 hv = hrow[kf ^ sw];
    float4 r4 = wr[kf];
    float4 z4 = wz[kf];
    float4 n4 = wn[kf];
    sr += hv.x * r4.x + hv.y * r4.y + hv.z * r4.z + hv.w * r4.w;
    sz += hv.x * z4.x + hv.y * z4.y + hv.z * z4.z + hv.w * z4.w;
    sn += hv.x * n4.x + hv.y * n4.y + hv.z * n4.z + hv.w * n4.w;
  }
  const float* g = gi + (size_t)b * 1536;
  float r = sigmoidf_(g[j] + sr + bhh[j]);
  float z = sigmoidf_(g[512 + j] + sz + bhh[512 + j]);
  float n = tanhf(g[1024 + j] + r * (sn + bhh[1024 + j]));
  float4 hj4 = hrow[(j >> 2) ^ sw];
  float hj = ((const float*)&hj4)[j & 3];
  h_out[b * 512 + j] = (1.f - z) * n + z * hj;
}

// ---------------- batch-shared GEMV: out[b,n] = bias[n] + X[b,:]·W[n,:] ----------------
// X[b,:] = concat(src1_row(b), src2_row(b)); src1_row = tokidx ? A1[tok[b]] : A1[b].
// One thread owns one n for ALL 32 batches (W read once, ÷32 traffic vs per-batch grid).
// 256 thr = 32 n × 8 k-slices (slice = tid&7, stride-8 float4 interleave → conflict-free
// LDS banks + 128B-contiguous W segments per wave-octet); shfl_xor reduce over slices.
// Requires: N %32==0, K %128==0, len1 %4==0. Chunks of 128 floats staged in 16KB LDS.
__global__ __launch_bounds__(256) void gemvB(
    const float* __restrict__ A1, const int* __restrict__ tokidx, int len1,
    const float* __restrict__ A2, int len2,
    const float* __restrict__ W, const float* __restrict__ bias,
    float* __restrict__ out0, float* __restrict__ out1, int split, int N, int K) {
  int tid = threadIdx.x;
  int s = tid & 7, nl = tid >> 3;
  int n = blockIdx.x * 32 + nl;
  __shared__ float4 xs4[32 * 32];
  float acc[32];
#pragma unroll
  for (int b = 0; b < 32; ++b) acc[b] = 0.f;
  const float4* W4 = (const float4*)(W + (size_t)n * K);
  int K4 = K >> 2;
  int len1_4 = len1 >> 2;
  for (int k0 = 0; k0 < K4; k0 += 32) {
    __syncthreads();
    for (int idx = tid; idx < 1024; idx += 256) {
      int b = idx >> 5, kf = idx & 31;
      int gk = k0 + kf;
      float4 v;
      if (gk < len1_4) {
        const float* src = tokidx ? (A1 + (size_t)tokidx[b] * len1) : (A1 + (size_t)b * len1);
        v = ((const float4*)src)[gk];
      } else {
        v = ((const float4*)(A2 + (size_t)b * len2))[gk - len1_4];
      }
      xs4[idx] = v;
    }
    __syncthreads();
    const float4* wp = W4 + k0;
#pragma unroll
    for (int j = 0; j < 4; ++j) {
      float4 wv = wp[j * 8 + s];
      const float4* xp = xs4 + j * 8 + s;
#pragma unroll
      for (int b = 0; b < 32; ++b) {
        float4 xv = xp[b * 32];
        acc[b] += wv.x * xv.x + wv.y * xv.y + wv.z * xv.z + wv.w * xv.w;
      }
    }
  }
#pragma unroll
  for (int b = 0; b < 32; ++b) {
    float v = acc[b];
    v += __shfl_xor(v, 1);
    v += __shfl_xor(v, 2);
    v += __shfl_xor(v, 4);
    acc[b] = v;
  }
  if (s == 0) {
    float bv = bias ? bias[n] : 0.f;
#pragma unroll
    for (int b = 0; b < 32; ++b) {
      float val = acc[b] + bv;
      if (n < split) out0[(size_t)b * split + n] = val;
      else out1[(size_t)b * (N - split) + (n - split)] = val;
    }
  }
}

// ---------------- fused attention (d precomputed by gemvB) ----------------
__global__ __launch_bounds__(512) void attention_kernel(
    const float* __restrict__ dbuf,     // [32][512] = h1 @ Wd^T
    const float* __restrict__ v,
    const float* __restrict__ enc_proj, // [32][128][512]
    const float* __restrict__ enc_out,  // [32][128][1024]
    float* __restrict__ ctx) {          // [32][1024]
  int b = blockIdx.x;
  int tid = threadIdx.x;
  __shared__ float d[512];
  __shared__ float red[512];
  __shared__ float sc[128];
  d[tid] = dbuf[b * 512 + tid];
  __syncthreads();
  {
    int t = tid >> 2, part = tid & 3;
    const float* ep = enc_proj + ((size_t)b * 128 + t) * 512 + part * 128;
    const float* dd = d + part * 128;
    const float* vv = v + part * 128;
    float s = 0.f;
    for (int a = 0; a < 128; ++a) s += tanhf(ep[a] + dd[a]) * vv[a];
    red[tid] = s;
  }
  __syncthreads();
  if (tid < 128) sc[tid] = red[tid * 4] + red[tid * 4 + 1] + red[tid * 4 + 2] + red[tid * 4 + 3];
  __syncthreads();
  if (tid == 0) {
    float m = -1e30f;
    for (int t = 0; t < 128; ++t) m = fmaxf(m, sc[t]);
    float sum = 0.f;
    for (int t = 0; t < 128; ++t) { float e = expf(sc[t] - m); sc[t] = e; sum += e; }
    float inv = 1.f / sum;
    for (int t = 0; t < 128; ++t) sc[t] *= inv;
  }
  __syncthreads();
  for (int e = tid; e < 1024; e += 512) {
    const float* eo = enc_out + (size_t)b * 131072 + e;
    float s = 0.f;
    for (int t = 0; t < 128; ++t) s += sc[t] * eo[(size_t)t * 1024];
    ctx[b * 1024 + e] = s;
  }
}

// ---------------- argmax (first-max tie-break, matches np.argmax) ----------------
__global__ __launch_bounds__(256) void argmax_kernel(
    const float* __restrict__ logits, int* __restrict__ tok,
    int* __restrict__ decoded, int step) {
  int b = blockIdx.x, tid = threadIdx.x;
  __shared__ float bv[256];
  __shared__ int bi[256];
  float best = -3.4e38f;
  int bidx = 0x7fffffff;
  const float* L = logits + (size_t)b * 8000;
  for (int v = tid; v < 8000; v += 256) {
    float x = L[v];
    if (x > best) { best = x; bidx = v; }
  }
  bv[tid] = best; bi[tid] = bidx;
  __syncthreads();
  for (int s = 128; s > 0; s >>= 1) {
    if (tid < s) {
      if (bv[tid + s] > bv[tid] || (bv[tid + s] == bv[tid] && bi[tid + s] < bi[tid])) {
        bv[tid] = bv[tid + s];
        bi[tid] = bi[tid + s];
      }
    }
    __syncthreads();
  }
  if (tid == 0) { tok[b] = bi[0]; decoded[b * 50 + step + 1] = bi[0]; }
}

__global__ void init_kernel(int* __restrict__ tok, int* __restrict__ decoded) {
  int b = threadIdx.x;
  if (b >= 32) return;
  tok[b] = 1;
  decoded[b * 50] = 1;
}

__global__ void zero_kernel(float* __restrict__ p, int n) {
  int i = blockIdx.x * 256 + threadIdx.x;
  if (i < n) p[i] = 0.f;
}

extern "C" void kernel_launch(void* const* d_in, const int* in_sizes, int n_in,
                              void* d_out, int out_size, void* d_ws, size_t ws_size,
                              hipStream_t stream) {
  const float* features  = (const float*)d_in[0];
  const float* conv_w1   = (const float*)d_in[1];
  const float* conv_b1   = (const float*)d_in[2];
  const float* conv_w2   = (const float*)d_in[3];
  const float* conv_b2   = (const float*)d_in[4];
  const float* enc_Wih_f = (const float*)d_in[5];
  const float* enc_Whh_f = (const float*)d_in[6];
  const float* enc_bih_f = (const float*)d_in[7];
  const float* enc_bhh_f = (const float*)d_in[8];
  const float* enc_Wih_b = (const float*)d_in[9];
  const float* enc_Whh_b = (const float*)d_in[10];
  const float* enc_bih_b = (const float*)d_in[11];
  const float* enc_bhh_b = (const float*)d_in[12];
  const float* bridge_W  = (const float*)d_in[13];
  const float* bridge_b  = (const float*)d_in[14];
  const float* emb       = (const float*)d_in[15];
  const float* attn_We   = (const float*)d_in[16];
  const float* attn_Wd   = (const float*)d_in[17];
  const float* attn_v    = (const float*)d_in[18];
  const float* dec_Wih0  = (const float*)d_in[19];
  const float* dec_Whh0  = (const float*)d_in[20];
  const float* dec_bih0  = (const float*)d_in[21];
  const float* dec_bhh0  = (const float*)d_in[22];
  const float* dec_Wih1  = (const float*)d_in[23];
  const float* dec_Whh1  = (const float*)d_in[24];
  const float* dec_bih1  = (const float*)d_in[25];
  const float* dec_bhh1  = (const float*)d_in[26];
  const float* proj_W    = (const float*)d_in[27];
  const float* proj_b    = (const float*)d_in[28];
  int* decoded = (int*)d_out;

  // ---- static workspace (non-overlapping layout) ----
  float* ws = nullptr;
  hipGetSymbolAddress((void**)&ws, HIP_SYMBOL(g_ws));
  float* P       = ws;                    // 10,485,760
  float* y1      = ws + 10485760;         //  4,194,304
  float* x2      = ws + 14680064;         //  2,097,152
  float* gi_f    = ws + 16777216;         //  6,291,456
  float* gi_b    = ws + 23068672;         //  6,291,456
  float* enc_out = ws + 29360128;         //  4,194,304
  float* enc_pj  = ws + 33554432;         //  2,097,152
  float* h_enc   = ws + 35651584;         //     65,536 (2 bufs x 2 dir x 32 x 512)
  float* h0d     = ws + 35717120;         //     32,768
  float* h1d     = ws + 35749888;         //     32,768
  float* ctxb    = ws + 35782656;         //     32,768
  float* gi0     = ws + 35815424;         //     49,152
  float* gi1     = ws + 35864576;         //     49,152
  float* logits  = ws + 35913728;         //    256,000
  float* dbuf    = ws + 36169728;         //     16,384
  int*   tok     = (int*)(ws + 36186112); //         32

  // ---- conv front-end as im2col + GEMM (+bias+relu) ----
  im2col1_kernel<<<40960, 256, 0, stream>>>(features, P);
  sgemm128<<<dim3(4, 64), 256, 0, stream>>>(P, conv_w1, conv_b1, y1, 8192, 512, 1280, 1);
  im2col2_kernel<<<40960, 256, 0, stream>>>(y1, P);
  sgemm128<<<dim3(4, 32), 256, 0, stream>>>(P, conv_w2, conv_b2, x2, 4096, 512, 2560, 1);

  // ---- GRU input transforms ----
  sgemm128<<<dim3(12, 32), 256, 0, stream>>>(x2, enc_Wih_f, enc_bih_f, gi_f, 4096, 1536, 512, 0);
  sgemm128<<<dim3(12, 32), 256, 0, stream>>>(x2, enc_Wih_b, enc_bih_b, gi_b, 4096, 1536, 512, 0);

  // ---- bidirectional encoder recurrence ----
  zero_kernel<<<256, 256, 0, stream>>>(h_enc, 65536);
  for (int s = 0; s < 128; ++s) {
    enc_gru_step<<<128, 256, 0, stream>>>(gi_f, gi_b,
        enc_Whh_f, enc_bhh_f, enc_Whh_b, enc_bhh_b,
        h_enc + (s & 1) * 32768, h_enc + ((s + 1) & 1) * 32768, enc_out, s);
  }
  float* h_fin = h_enc;  // final state in buffer 0 after 128 steps

  // ---- bridge (h0d, h1d via split) ----
  gemvB<<<32, 256, 0, stream>>>(h_fin, nullptr, 512, h_fin + 16384, 512,
      bridge_W, bridge_b, h0d, h1d, 512, 1024, 1024);

  // ---- enc_proj ----
  sgemm128<<<dim3(4, 32), 256, 0, stream>>>(enc_out, attn_We, nullptr, enc_pj, 4096, 512, 1024, 0);

  init_kernel<<<1, 64, 0, stream>>>(tok, decoded);

  // ---- greedy attention decoder, 49 steps ----
  for (int s = 0; s < 49; ++s) {
    int cur = s & 1, nxt = (s + 1) & 1;
    gemvB<<<16, 256, 0, stream>>>(h1d + cur * 16384, nullptr, 512, nullptr, 0,
        attn_Wd, nullptr, dbuf, nullptr, 512, 512, 512);
    attention_kernel<<<32, 512, 0, stream>>>(dbuf, attn_v, enc_pj, enc_out, ctxb);
    gemvB<<<48, 256, 0, stream>>>(emb, tok, 512, ctxb, 1024,
        dec_Wih0, dec_bih0, gi0, nullptr, 1536, 1536, 1536);
    dec_gru_step<<<64, 256, 0, stream>>>(gi0, dec_Whh0, dec_bhh0,
        h0d + cur * 16384, h0d + nxt * 16384);
    gemvB<<<48, 256, 0, stream>>>(h0d + nxt * 16384, nullptr, 512, nullptr, 0,
        dec_Wih1, dec_bih1, gi1, nullptr, 1536, 1536, 512);
    dec_gru_step<<<64, 256, 0, stream>>>(gi1, dec_Whh1, dec_bhh1,
        h1d + cur * 16384, h1d + nxt * 16384);
    gemvB<<<250, 256, 0, stream>>>(h1d + nxt * 16384, nullptr, 512, ctxb, 1024,
        proj_W, proj_b, logits, nullptr, 8000, 8000, 1536);
    argmax_kernel<<<32, 256, 0, stream>>>(logits, tok, decoded, s);
  }
}